// Round 10
// baseline (246.436 us; speedup 1.0000x reference)
//
#include <hip/hip_runtime.h>
#include <hip/hip_bf16.h>
#include <math.h>

#define NN 20000
#define EE 640000
#define NCH 16        // source-node chunks for counting sort
#define CHN 1250      // nodes per chunk

typedef __attribute__((ext_vector_type(8))) short short8;
typedef __attribute__((ext_vector_type(4))) float f32x4;
typedef __hip_bfloat16 bf16;
typedef __hip_bfloat162 bf162;

__device__ inline ushort f2bf(float f) {
  bf16 h = __float2bfloat16(f);
  return *(ushort*)&h;
}
__device__ inline float2 bf2u(uint u) {
  return __bfloat1622float2(*(const bf162*)&u);
}
__device__ inline float fast_tanh(float x) {
  float xx = fminf(fmaxf(x, -9.0f), 9.0f);
  float e = exp2f(xx * 2.885390082f);  // 2*log2(e)
  return (e - 1.0f) * __builtin_amdgcn_rcpf(e + 1.0f);
}
__device__ inline short8 frag_from_f32(const float* p) {
  float4 f0 = *(const float4*)p;
  float4 f1 = *(const float4*)(p + 4);
  ushort tmp[8] = {f2bf(f0.x), f2bf(f0.y), f2bf(f0.z), f2bf(f0.w),
                   f2bf(f1.x), f2bf(f1.y), f2bf(f1.z), f2bf(f1.w)};
  return *(const short8*)tmp;
}

// ---------------------------------------------------------------------------
// Buffers: kbuf / vbuf / bbuf are separate [NN][128] bf16 arrays (256 B rows).
// scol holds each node's edge list COUNTING-SORTED by source chunk (c/1250):
// qkv counts into cnt2[n][16]; vb prefix-sums in place; scatter places edges
// at bucket offsets.  Aggregate is the proven round-9 structure, unchanged —
// sorted order turns its random gather into a sliding ~1 MB window.
// ---------------------------------------------------------------------------

// ---------------------------------------------------------------------------
// Kernel 1 (grid 157x3): lean GEMM C = x@W + b via bf16 MFMA.
// ONLY W is staged in LDS (34.8 KB); A-fragments loaded directly from global x
// (K contiguous).  __launch_bounds__(256,4) keeps VGPR <=128.
// Grid-stride prologue: per-(node,chunk) edge counts (cnt2 pre-zeroed).
// ---------------------------------------------------------------------------
__global__ __launch_bounds__(256, 4) void qkv_gemm(
    const float* __restrict__ x,
    const float* __restrict__ Wq, const float* __restrict__ bq,
    const float* __restrict__ Wk, const float* __restrict__ bk,
    const float* __restrict__ Wv, const float* __restrict__ bv,
    const int* __restrict__ ei,
    float* __restrict__ qbuf,
    ushort* __restrict__ kbuf, ushort* __restrict__ vbuf,
    int* __restrict__ cnt2) {
  __shared__ ushort WB[128 * 136];
  int t = threadIdx.x;
  int n0 = blockIdx.x * 128;
  int mat = blockIdx.y;  // 0=q 1=k 2=v

  { // grid-stride count pass
    int flat = (mat * 157 + blockIdx.x) * 256 + t;
    for (int e = flat; e < EE; e += 157 * 3 * 256) {
      int r = ei[e];
      int c = ei[EE + e];
      atomicAdd(&cnt2[r * NCH + c / CHN], 1);
    }
  }

  const float* W    = mat == 0 ? Wq : (mat == 1 ? Wk : Wv);
  const float* bias = mat == 0 ? bq : (mat == 1 ? bk : bv);

  { // stage: transpose W (128x128 fp32, k-major) -> WB[col][k] bf16
    int k = t >> 1, nh = (t & 1) * 64;
    const float* src = W + (size_t)k * 128 + nh;
#pragma unroll
    for (int i = 0; i < 16; ++i) {
      float4 f = *(const float4*)(src + 4 * i);
      WB[(nh + 4 * i + 0) * 136 + k] = f2bf(f.x);
      WB[(nh + 4 * i + 1) * 136 + k] = f2bf(f.y);
      WB[(nh + 4 * i + 2) * 136 + k] = f2bf(f.z);
      WB[(nh + 4 * i + 3) * 136 + k] = f2bf(f.w);
    }
  }
  __syncthreads();

  int w = t >> 6, lane = t & 63;
  int m = lane & 15, q = lane >> 4;
  int r0 = w * 32;
  int row0 = n0 + r0 + m;
  int row1 = row0 + 16;
  bool ok0 = row0 < NN, ok1 = row1 < NN;
  const float* xr0 = x + (size_t)row0 * 128;
  const float* xr1 = x + (size_t)row1 * 128;
  const short8 z8 = (short8){0, 0, 0, 0, 0, 0, 0, 0};

  f32x4 acc0[8], acc1[8];
#pragma unroll
  for (int c = 0; c < 8; ++c) {
    acc0[c] = (f32x4){0.f, 0.f, 0.f, 0.f};
    acc1[c] = (f32x4){0.f, 0.f, 0.f, 0.f};
  }
#pragma unroll
  for (int kt = 0; kt < 4; ++kt) {
    int kof = kt * 32 + 8 * q;
    short8 a0 = ok0 ? frag_from_f32(xr0 + kof) : z8;
    short8 a1 = ok1 ? frag_from_f32(xr1 + kof) : z8;
#pragma unroll
    for (int c = 0; c < 8; ++c) {
      short8 b = *(const short8*)&WB[(c * 16 + m) * 136 + kof];
      acc0[c] = __builtin_amdgcn_mfma_f32_16x16x32_bf16(a0, b, acc0[c], 0, 0, 0);
      acc1[c] = __builtin_amdgcn_mfma_f32_16x16x32_bf16(a1, b, acc1[c], 0, 0, 0);
    }
  }
  // epilogue: D[row][col], row = 4q+reg (+16), col = 16c+m
  if (mat == 0) {
#pragma unroll
    for (int c = 0; c < 8; ++c) {
      int col = c * 16 + m;
      float bb = bias[col];
#pragma unroll
      for (int reg = 0; reg < 4; ++reg) {
        int ra = n0 + r0 + 4 * q + reg;
        int rb = ra + 16;
        if (ra < NN) qbuf[(size_t)ra * 128 + col] = acc0[c][reg] + bb;
        if (rb < NN) qbuf[(size_t)rb * 128 + col] = acc1[c][reg] + bb;
      }
    }
  } else {
    ushort* dst = (mat == 1) ? kbuf : vbuf;
#pragma unroll
    for (int c = 0; c < 8; ++c) {
      int col = c * 16 + m;
      float bb = bias[col];
#pragma unroll
      for (int reg = 0; reg < 4; ++reg) {
        int ra = n0 + r0 + 4 * q + reg;
        int rb = ra + 16;
        if (ra < NN) dst[(size_t)ra * 128 + col] = f2bf(acc0[c][reg] + bb);
        if (rb < NN) dst[(size_t)rb * 128 + col] = f2bf(acc1[c][reg] + bb);
      }
    }
  }
}

// ---------------------------------------------------------------------------
// Kernel 2: bbuf[n,h,:] = tanh(vbuf[n,h,:] @ Wpsi + bpsi), one thread/(n,h).
// Threads with idx < NN additionally prefix-sum cnt2[idx][0..15] in place
// (exclusive) and write the capped total to cursor[idx].
// ---------------------------------------------------------------------------
__global__ __launch_bounds__(256) void vb_kernel(
    const ushort* __restrict__ vbuf, ushort* __restrict__ bbuf,
    const float* __restrict__ Wpsi, const float* __restrict__ bpsi,
    int* __restrict__ cnt2, int* __restrict__ cursor) {
  __shared__ float Ws[256];
  __shared__ float bs[16];
  int t = threadIdx.x;
  Ws[t] = Wpsi[t];
  if (t < 16) bs[t] = bpsi[t];
  __syncthreads();
  int idx = blockIdx.x * 256 + t;

  if (idx < NN) {  // per-node exclusive prefix over 16 chunk counts
    int* p = cnt2 + idx * NCH;
    int run = 0;
#pragma unroll
    for (int j = 0; j < NCH; ++j) {
      int v = p[j];
      p[j] = run;
      run += v;
    }
    cursor[idx] = run > 128 ? 128 : run;
  }

  int n = idx >> 3, h = idx & 7;
  const ushort* vp = vbuf + (size_t)n * 128 + h * 16;
  uint4 a = *(const uint4*)vp;
  uint4 b = *(const uint4*)(vp + 8);
  float v[16];
  {
    float2 f;
    f = bf2u(a.x); v[0] = f.x;  v[1] = f.y;
    f = bf2u(a.y); v[2] = f.x;  v[3] = f.y;
    f = bf2u(a.z); v[4] = f.x;  v[5] = f.y;
    f = bf2u(a.w); v[6] = f.x;  v[7] = f.y;
    f = bf2u(b.x); v[8] = f.x;  v[9] = f.y;
    f = bf2u(b.y); v[10] = f.x; v[11] = f.y;
    f = bf2u(b.z); v[12] = f.x; v[13] = f.y;
    f = bf2u(b.w); v[14] = f.x; v[15] = f.y;
  }
  float o[16];
#pragma unroll
  for (int d = 0; d < 16; ++d) o[d] = bs[d];
#pragma unroll
  for (int dp = 0; dp < 16; ++dp) {
    float vv = v[dp];
#pragma unroll
    for (int d = 0; d < 16; ++d) o[d] = fmaf(vv, Ws[dp * 16 + d], o[d]);
  }
  ushort* dst = bbuf + (size_t)n * 128 + h * 16;
  uint u[8];
#pragma unroll
  for (int j = 0; j < 8; ++j)
    u[j] = (uint)f2bf(fast_tanh(o[2 * j])) |
           ((uint)f2bf(fast_tanh(o[2 * j + 1])) << 16);
  *(uint4*)dst = *(const uint4*)&u[0];
  *(uint4*)(dst + 8) = *(const uint4*)&u[4];
}

// ---------------------------------------------------------------------------
// Kernel 3: placement pass of the counting sort — each edge goes to its
// node's bucket offset, so scol[node][0..cnt) is sorted by source chunk.
// ---------------------------------------------------------------------------
__global__ __launch_bounds__(256) void scatter_kernel(
    const int* __restrict__ ei,
    int* __restrict__ cnt2, ushort* __restrict__ scol) {
  int e = blockIdx.x * 256 + threadIdx.x;
  if (e < EE) {
    int r = ei[e];
    int c = ei[EE + e];
    int pos = atomicAdd(&cnt2[r * NCH + c / CHN], 1);
    if (pos < 128) scol[r * 128 + pos] = (ushort)c;
  }
}

// ---------------------------------------------------------------------------
// Kernel 4: one wave per destination node (proven ~62us structure, verbatim
// round 9).  Per edge: 3 uint gathers + 3-shfl dot reduce + exp2; 8-edge
// batches.  q pre-scaled by (1/sqrt(16))*log2(e) so w = exp2(dot).
// ---------------------------------------------------------------------------
__global__ __launch_bounds__(256) void aggregate_kernel(
    const float* __restrict__ qbuf,
    const ushort* __restrict__ kbuf, const ushort* __restrict__ vbuf,
    const ushort* __restrict__ bbuf,
    const int* __restrict__ cursor, const ushort* __restrict__ scol,
    ushort* __restrict__ hbufb) {
  int wid = threadIdx.x >> 6, lane = threadIdx.x & 63;
  int node = blockIdx.x * 4 + wid;
  int h = lane >> 3, dg = (lane & 7) * 2;
  int off = h * 16 + dg;
  const float SC = 0.25f * 1.44269504f;
  float2 q2 = *(const float2*)(qbuf + (size_t)node * 128 + off);
  q2.x *= SC; q2.y *= SC;
  int cnt = cursor[node];
  const ushort* srow = scol + node * 128;
  float s = 0.f, aV0 = 0.f, aV1 = 0.f, aB0 = 0.f, aB1 = 0.f;

  auto proc1 = [&](uint K, uint V, uint B) {
    float2 kk = bf2u(K);
    float d = fmaf(q2.x, kk.x, q2.y * kk.y);
    d += __shfl_xor(d, 1);
    d += __shfl_xor(d, 2);
    d += __shfl_xor(d, 4);
    float wgt = exp2f(d);
    s += wgt;
    float2 vv = bf2u(V);
    aV0 = fmaf(wgt, vv.x, aV0); aV1 = fmaf(wgt, vv.y, aV1);
    float2 tb = bf2u(B);
    aB0 = fmaf(wgt, tb.x, aB0); aB1 = fmaf(wgt, tb.y, aB1);
  };

  int i = 0;
  for (; i + 8 <= cnt; i += 8) {
    uint4 wv = *(const uint4*)(srow + i);
    int id[8] = {(int)(wv.x & 0xffffu), (int)(wv.x >> 16),
                 (int)(wv.y & 0xffffu), (int)(wv.y >> 16),
                 (int)(wv.z & 0xffffu), (int)(wv.z >> 16),
                 (int)(wv.w & 0xffffu), (int)(wv.w >> 16)};
    uint K[8], V[8], B[8];
#pragma unroll
    for (int j = 0; j < 8; ++j) {
      size_t base = (size_t)id[j] * 128 + off;
      K[j] = *(const uint*)(kbuf + base);
      V[j] = *(const uint*)(vbuf + base);
      B[j] = *(const uint*)(bbuf + base);
    }
#pragma unroll
    for (int j = 0; j < 8; ++j) proc1(K[j], V[j], B[j]);
  }
  for (; i < cnt; ++i) {
    int e = srow[i];
    size_t base = (size_t)e * 128 + off;
    proc1(*(const uint*)(kbuf + base), *(const uint*)(vbuf + base),
          *(const uint*)(bbuf + base));
  }

  float inv = s > 0.f ? 1.f / s : 0.f;
  ushort* hp = hbufb + (size_t)node * 256 + off;
  uint uv = (uint)f2bf(aV0 * inv) | ((uint)f2bf(aV1 * inv) << 16);
  uint ub = (uint)f2bf(aB0 * inv) | ((uint)f2bf(aB1 * inv) << 16);
  *(uint*)(hp)       = uv;
  *(uint*)(hp + 128) = ub;
}

// ---------------------------------------------------------------------------
// Kernel 5: out = LN(x + relu(h @ Wo + bo)) * gamma + beta via bf16 MFMA.
// Lean: only Wo chunk in LDS; A-fragments straight from hbufb (verbatim r9).
// ---------------------------------------------------------------------------
__global__ __launch_bounds__(256, 4) void output_mfma(
    const ushort* __restrict__ hbufb, const float* __restrict__ x,
    const float* __restrict__ Wo, const float* __restrict__ bo,
    const float* __restrict__ gamma, const float* __restrict__ beta,
    float* __restrict__ out) {
  __shared__ ushort WB[128 * 136];
  __shared__ float bos[128], gs[128], bts[128];
  int t = threadIdx.x;
  int n0 = blockIdx.x * 128;
  if (t < 128) { bos[t] = bo[t]; gs[t] = gamma[t]; bts[t] = beta[t]; }
  int w = t >> 6, lane = t & 63;
  int m = lane & 15, q = lane >> 4;
  int r0 = w * 32;
  int row0 = n0 + r0 + m;
  int row1 = row0 + 16;
  bool ok0 = row0 < NN, ok1 = row1 < NN;
  const ushort* hr0 = hbufb + (size_t)row0 * 256;
  const ushort* hr1 = hbufb + (size_t)row1 * 256;
  const short8 z8 = (short8){0, 0, 0, 0, 0, 0, 0, 0};

  f32x4 acc0[8], acc1[8];
#pragma unroll
  for (int c = 0; c < 8; ++c) {
    acc0[c] = (f32x4){0.f, 0.f, 0.f, 0.f};
    acc1[c] = (f32x4){0.f, 0.f, 0.f, 0.f};
  }
  for (int kc = 0; kc < 2; ++kc) {
    if (kc) __syncthreads();
    { // stage Wo chunk: rows kc*128..+127 (K), cols 0..127 -> WB[col][k]
      int k = t >> 1, nh = (t & 1) * 64;
      const float* src = Wo + (size_t)(kc * 128 + k) * 128 + nh;
#pragma unroll
      for (int i = 0; i < 16; ++i) {
        float4 f = *(const float4*)(src + 4 * i);
        WB[(nh + 4 * i + 0) * 136 + k] = f2bf(f.x);
        WB[(nh + 4 * i + 1) * 136 + k] = f2bf(f.y);
        WB[(nh + 4 * i + 2) * 136 + k] = f2bf(f.z);
        WB[(nh + 4 * i + 3) * 136 + k] = f2bf(f.w);
      }
    }
    __syncthreads();
#pragma unroll
    for (int kt = 0; kt < 4; ++kt) {
      int kof = kt * 32 + 8 * q;
      short8 a0 = ok0 ? *(const short8*)(hr0 + kc * 128 + kof) : z8;
      short8 a1 = ok1 ? *(const short8*)(hr1 + kc * 128 + kof) : z8;
#pragma unroll
      for (int c = 0; c < 8; ++c) {
        short8 b = *(const short8*)&WB[(c * 16 + m) * 136 + kof];
        acc0[c] = __builtin_amdgcn_mfma_f32_16x16x32_bf16(a0, b, acc0[c], 0, 0, 0);
        acc1[c] = __builtin_amdgcn_mfma_f32_16x16x32_bf16(a1, b, acc1[c], 0, 0, 0);
      }
    }
  }
  // epilogue: relu + residual + LayerNorm, all in registers
#pragma unroll
  for (int half = 0; half < 2; ++half) {
#pragma unroll
    for (int reg = 0; reg < 4; ++reg) {
      int row = n0 + r0 + half * 16 + 4 * q + reg;
      bool valid = row < NN;
      float vals[8];
      float sum = 0.f;
#pragma unroll
      for (int c = 0; c < 8; ++c) {
        int col = c * 16 + m;
        float a = (half ? acc1[c][reg] : acc0[c][reg]) + bos[col];
        a = fmaxf(a, 0.f);
        float xv = valid ? x[(size_t)row * 128 + col] : 0.f;
        float v = a + xv;
        vals[c] = v;
        sum += v;
      }
      sum += __shfl_xor(sum, 1); sum += __shfl_xor(sum, 2);
      sum += __shfl_xor(sum, 4); sum += __shfl_xor(sum, 8);
      float mean = sum * (1.f / 128.f);
      float ssq = 0.f;
#pragma unroll
      for (int c = 0; c < 8; ++c) {
        float d = vals[c] - mean;
        ssq = fmaf(d, d, ssq);
      }
      ssq += __shfl_xor(ssq, 1); ssq += __shfl_xor(ssq, 2);
      ssq += __shfl_xor(ssq, 4); ssq += __shfl_xor(ssq, 8);
      float rstd = rsqrtf(ssq * (1.f / 128.f) + 1e-5f);
      if (valid) {
#pragma unroll
        for (int c = 0; c < 8; ++c) {
          int col = c * 16 + m;
          out[(size_t)row * 128 + col] = (vals[c] - mean) * rstd * gs[col] + bts[col];
        }
      }
    }
  }
}

// ---------------------------------------------------------------------------
extern "C" void kernel_launch(void* const* d_in, const int* in_sizes, int n_in,
                              void* d_out, int out_size, void* d_ws, size_t ws_size,
                              hipStream_t stream) {
  const float* x     = (const float*)d_in[0];
  const int*   ei    = (const int*)d_in[1];
  const float* Wq    = (const float*)d_in[2];
  const float* bq    = (const float*)d_in[3];
  const float* Wk    = (const float*)d_in[4];
  const float* bk    = (const float*)d_in[5];
  const float* Wv    = (const float*)d_in[6];
  const float* bv    = (const float*)d_in[7];
  const float* Wpsi  = (const float*)d_in[8];
  const float* bpsi  = (const float*)d_in[9];
  const float* Wo    = (const float*)d_in[10];
  const float* bo    = (const float*)d_in[11];
  const float* gamma = (const float*)d_in[12];
  const float* beta  = (const float*)d_in[13];
  float* out = (float*)d_out;

  char* ws = (char*)d_ws;
  float*  qbuf   = (float*) (ws);               // 10,240,000 B
  ushort* kbuf   = (ushort*)(ws + 10240000);    //  5,120,000 B
  ushort* vbuf   = (ushort*)(ws + 15360000);    //  5,120,000 B
  ushort* bbuf   = (ushort*)(ws + 20480000);    //  5,120,000 B
  ushort* hbufb  = (ushort*)(ws + 25600000);    // 10,240,000 B
  int*    cursor = (int*)   (ws + 35840000);    //     80,000 B
  int*    cnt2   = (int*)   (ws + 35920000);    //  1,280,000 B
  ushort* scol   = (ushort*)(ws + 37200000);    //  5,120,000 B  (~42.3 MB)

  hipMemsetAsync(cnt2, 0, 1280000, stream);

  qkv_gemm<<<dim3(157, 3), 256, 0, stream>>>(x, Wq, bq, Wk, bk, Wv, bv, ei,
                                             qbuf, kbuf, vbuf, cnt2);
  vb_kernel<<<625, 256, 0, stream>>>(vbuf, bbuf, Wpsi, bpsi, cnt2, cursor);
  scatter_kernel<<<2500, 256, 0, stream>>>(ei, cnt2, scol);
  aggregate_kernel<<<5000, 256, 0, stream>>>(qbuf, kbuf, vbuf, bbuf,
                                             cursor, scol, hbufb);
  output_mfma<<<157, 256, 0, stream>>>(hbufb, x, Wo, bo, gamma, beta, out);
}

// Round 11
// 222.807 us; speedup vs baseline: 1.1060x; 1.1060x over previous
//
#include <hip/hip_runtime.h>
#include <hip/hip_bf16.h>
#include <math.h>

#define NN 20000
#define EE 640000

typedef __attribute__((ext_vector_type(8))) short short8;
typedef __attribute__((ext_vector_type(4))) float f32x4;
typedef __hip_bfloat16 bf16;
typedef __hip_bfloat162 bf162;

__device__ inline ushort f2bf(float f) {
  bf16 h = __float2bfloat16(f);
  return *(ushort*)&h;
}
__device__ inline float2 bf2u(uint u) {
  return __bfloat1622float2(*(const bf162*)&u);
}
__device__ inline float fast_tanh(float x) {
  float xx = fminf(fmaxf(x, -9.0f), 9.0f);
  float e = exp2f(xx * 2.885390082f);  // 2*log2(e)
  return (e - 1.0f) * __builtin_amdgcn_rcpf(e + 1.0f);
}
__device__ inline short8 frag_from_f32(const float* p) {
  float4 f0 = *(const float4*)p;
  float4 f1 = *(const float4*)(p + 4);
  ushort tmp[8] = {f2bf(f0.x), f2bf(f0.y), f2bf(f0.z), f2bf(f0.w),
                   f2bf(f1.x), f2bf(f1.y), f2bf(f1.z), f2bf(f1.w)};
  return *(const short8*)tmp;
}

// ---------------------------------------------------------------------------
// Buffers: kbuf / vbuf / bbuf are separate [NN][128] bf16 arrays (256 B rows).
// Aggregate: round-9 proven structure verbatim (~58-62us, FETCH-bound on the
// random gather).  This round only removes dispatches: scatter and vb are
// fused into qkv_gemm; stream = memset + 3 kernels.
// ---------------------------------------------------------------------------

// ---------------------------------------------------------------------------
// Kernel 1 (grid 157x3): lean GEMM C = x@W + b via bf16 MFMA.
// ONLY W staged in LDS (34.8 KB + 1.1 KB Wpsi); A-fragments loaded directly
// from global x.  __launch_bounds__(256,4) keeps VGPR <=128.
// Prologue: grid-stride edge scatter (cursor pre-zeroed by hipMemsetAsync).
// mat==2 epilogue: v tile bounced through WB (free after MFMA), per-thread
// vb = tanh(v @ Wpsi + bpsi) -> bbuf coalesced.  Bit-identical to the
// standalone vb kernel (same bf16 values in, same ops).
// ---------------------------------------------------------------------------
__global__ __launch_bounds__(256, 4) void qkv_gemm(
    const float* __restrict__ x,
    const float* __restrict__ Wq, const float* __restrict__ bq,
    const float* __restrict__ Wk, const float* __restrict__ bk,
    const float* __restrict__ Wv, const float* __restrict__ bv,
    const float* __restrict__ Wpsi, const float* __restrict__ bpsi,
    const int* __restrict__ ei,
    float* __restrict__ qbuf,
    ushort* __restrict__ kbuf, ushort* __restrict__ vbuf,
    ushort* __restrict__ bbuf,
    int* __restrict__ cursor, ushort* __restrict__ scol) {
  __shared__ ushort WB[128 * 136];
  __shared__ float Wps[256];
  __shared__ float bps[16];
  int t = threadIdx.x;
  int n0 = blockIdx.x * 128;
  int mat = blockIdx.y;  // 0=q 1=k 2=v

  { // grid-stride edge scatter (one atomic pass; overlaps W staging)
    int flat = (mat * 157 + blockIdx.x) * 256 + t;
    for (int e = flat; e < EE; e += 157 * 3 * 256) {
      int r = ei[e];
      int c = ei[EE + e];
      int pos = atomicAdd(&cursor[r], 1);
      if (pos < 128) scol[r * 128 + pos] = (ushort)c;
    }
  }

  const float* W    = mat == 0 ? Wq : (mat == 1 ? Wk : Wv);
  const float* bias = mat == 0 ? bq : (mat == 1 ? bk : bv);
  if (mat == 2) {
    Wps[t] = Wpsi[t];
    if (t < 16) bps[t] = bpsi[t];
  }

  { // stage: transpose W (128x128 fp32, k-major) -> WB[col][k] bf16
    int k = t >> 1, nh = (t & 1) * 64;
    const float* src = W + (size_t)k * 128 + nh;
#pragma unroll
    for (int i = 0; i < 16; ++i) {
      float4 f = *(const float4*)(src + 4 * i);
      WB[(nh + 4 * i + 0) * 136 + k] = f2bf(f.x);
      WB[(nh + 4 * i + 1) * 136 + k] = f2bf(f.y);
      WB[(nh + 4 * i + 2) * 136 + k] = f2bf(f.z);
      WB[(nh + 4 * i + 3) * 136 + k] = f2bf(f.w);
    }
  }
  __syncthreads();

  int w = t >> 6, lane = t & 63;
  int m = lane & 15, q = lane >> 4;
  int r0 = w * 32;
  int row0 = n0 + r0 + m;
  int row1 = row0 + 16;
  bool ok0 = row0 < NN, ok1 = row1 < NN;
  const float* xr0 = x + (size_t)row0 * 128;
  const float* xr1 = x + (size_t)row1 * 128;
  const short8 z8 = (short8){0, 0, 0, 0, 0, 0, 0, 0};

  f32x4 acc0[8], acc1[8];
#pragma unroll
  for (int c = 0; c < 8; ++c) {
    acc0[c] = (f32x4){0.f, 0.f, 0.f, 0.f};
    acc1[c] = (f32x4){0.f, 0.f, 0.f, 0.f};
  }
#pragma unroll
  for (int kt = 0; kt < 4; ++kt) {
    int kof = kt * 32 + 8 * q;
    short8 a0 = ok0 ? frag_from_f32(xr0 + kof) : z8;
    short8 a1 = ok1 ? frag_from_f32(xr1 + kof) : z8;
#pragma unroll
    for (int c = 0; c < 8; ++c) {
      short8 b = *(const short8*)&WB[(c * 16 + m) * 136 + kof];
      acc0[c] = __builtin_amdgcn_mfma_f32_16x16x32_bf16(a0, b, acc0[c], 0, 0, 0);
      acc1[c] = __builtin_amdgcn_mfma_f32_16x16x32_bf16(a1, b, acc1[c], 0, 0, 0);
    }
  }
  // epilogue: D[row][col], row = 4q+reg (+16), col = 16c+m
  if (mat == 0) {
#pragma unroll
    for (int c = 0; c < 8; ++c) {
      int col = c * 16 + m;
      float bb = bias[col];
#pragma unroll
      for (int reg = 0; reg < 4; ++reg) {
        int ra = n0 + r0 + 4 * q + reg;
        int rb = ra + 16;
        if (ra < NN) qbuf[(size_t)ra * 128 + col] = acc0[c][reg] + bb;
        if (rb < NN) qbuf[(size_t)rb * 128 + col] = acc1[c][reg] + bb;
      }
    }
  } else {
    ushort* dst = (mat == 1) ? kbuf : vbuf;
    if (mat == 2) __syncthreads();  // all waves done reading WB -> reusable
#pragma unroll
    for (int c = 0; c < 8; ++c) {
      int col = c * 16 + m;
      float bb = bias[col];
#pragma unroll
      for (int reg = 0; reg < 4; ++reg) {
        int ra = n0 + r0 + 4 * q + reg;
        int rb = ra + 16;
        ushort h0 = f2bf(acc0[c][reg] + bb);
        ushort h1 = f2bf(acc1[c][reg] + bb);
        if (ra < NN) dst[(size_t)ra * 128 + col] = h0;
        if (rb < NN) dst[(size_t)rb * 128 + col] = h1;
        if (mat == 2) {  // stash v tile in WB for the fused vb pass
          WB[(r0 + 4 * q + reg) * 136 + col] = h0;
          WB[(r0 + 16 + 4 * q + reg) * 136 + col] = h1;
        }
      }
    }
    if (mat == 2) {
      __syncthreads();
      // vb = tanh(v @ Wpsi + bpsi): 128 rows x 8 heads, 4 cells/thread
#pragma unroll
      for (int ii = 0; ii < 4; ++ii) {
        int cell = ii * 256 + t;
        int rl = cell >> 3, h = cell & 7;
        int n = n0 + rl;
        const ushort* vp = &WB[rl * 136 + h * 16];
        uint4 a = *(const uint4*)vp;
        uint4 b = *(const uint4*)(vp + 8);
        float v[16];
        {
          float2 f;
          f = bf2u(a.x); v[0] = f.x;  v[1] = f.y;
          f = bf2u(a.y); v[2] = f.x;  v[3] = f.y;
          f = bf2u(a.z); v[4] = f.x;  v[5] = f.y;
          f = bf2u(a.w); v[6] = f.x;  v[7] = f.y;
          f = bf2u(b.x); v[8] = f.x;  v[9] = f.y;
          f = bf2u(b.y); v[10] = f.x; v[11] = f.y;
          f = bf2u(b.z); v[12] = f.x; v[13] = f.y;
          f = bf2u(b.w); v[14] = f.x; v[15] = f.y;
        }
        float o[16];
#pragma unroll
        for (int d = 0; d < 16; ++d) o[d] = bps[d];
#pragma unroll
        for (int dp = 0; dp < 16; ++dp) {
          float vv = v[dp];
#pragma unroll
          for (int d = 0; d < 16; ++d) o[d] = fmaf(vv, Wps[dp * 16 + d], o[d]);
        }
        if (n < NN) {
          ushort* db = bbuf + (size_t)n * 128 + h * 16;
          uint u[8];
#pragma unroll
          for (int j = 0; j < 8; ++j)
            u[j] = (uint)f2bf(fast_tanh(o[2 * j])) |
                   ((uint)f2bf(fast_tanh(o[2 * j + 1])) << 16);
          *(uint4*)db = *(const uint4*)&u[0];
          *(uint4*)(db + 8) = *(const uint4*)&u[4];
        }
      }
    }
  }
}

// ---------------------------------------------------------------------------
// Kernel 2: one wave per destination node (round-9 proven structure verbatim).
// Per edge: 3 uint gathers (k,v,b) + 3-shfl dot reduce + exp2; 8-edge batches.
// q pre-scaled by (1/sqrt(16)) * log2(e) so w = exp2(dot).  Output bf16.
// ---------------------------------------------------------------------------
__global__ __launch_bounds__(256) void aggregate_kernel(
    const float* __restrict__ qbuf,
    const ushort* __restrict__ kbuf, const ushort* __restrict__ vbuf,
    const ushort* __restrict__ bbuf,
    const int* __restrict__ cursor, const ushort* __restrict__ scol,
    ushort* __restrict__ hbufb) {
  int wid = threadIdx.x >> 6, lane = threadIdx.x & 63;
  int node = blockIdx.x * 4 + wid;
  int h = lane >> 3, dg = (lane & 7) * 2;
  int off = h * 16 + dg;
  const float SC = 0.25f * 1.44269504f;
  float2 q2 = *(const float2*)(qbuf + (size_t)node * 128 + off);
  q2.x *= SC; q2.y *= SC;
  int cnt = cursor[node];
  cnt = cnt > 128 ? 128 : cnt;
  const ushort* srow = scol + node * 128;
  float s = 0.f, aV0 = 0.f, aV1 = 0.f, aB0 = 0.f, aB1 = 0.f;

  auto proc1 = [&](uint K, uint V, uint B) {
    float2 kk = bf2u(K);
    float d = fmaf(q2.x, kk.x, q2.y * kk.y);
    d += __shfl_xor(d, 1);
    d += __shfl_xor(d, 2);
    d += __shfl_xor(d, 4);
    float wgt = exp2f(d);
    s += wgt;
    float2 vv = bf2u(V);
    aV0 = fmaf(wgt, vv.x, aV0); aV1 = fmaf(wgt, vv.y, aV1);
    float2 tb = bf2u(B);
    aB0 = fmaf(wgt, tb.x, aB0); aB1 = fmaf(wgt, tb.y, aB1);
  };

  int i = 0;
  for (; i + 8 <= cnt; i += 8) {
    uint4 wv = *(const uint4*)(srow + i);
    int id[8] = {(int)(wv.x & 0xffffu), (int)(wv.x >> 16),
                 (int)(wv.y & 0xffffu), (int)(wv.y >> 16),
                 (int)(wv.z & 0xffffu), (int)(wv.z >> 16),
                 (int)(wv.w & 0xffffu), (int)(wv.w >> 16)};
    uint K[8], V[8], B[8];
#pragma unroll
    for (int j = 0; j < 8; ++j) {
      size_t base = (size_t)id[j] * 128 + off;
      K[j] = *(const uint*)(kbuf + base);
      V[j] = *(const uint*)(vbuf + base);
      B[j] = *(const uint*)(bbuf + base);
    }
#pragma unroll
    for (int j = 0; j < 8; ++j) proc1(K[j], V[j], B[j]);
  }
  for (; i < cnt; ++i) {
    int e = srow[i];
    size_t base = (size_t)e * 128 + off;
    proc1(*(const uint*)(kbuf + base), *(const uint*)(vbuf + base),
          *(const uint*)(bbuf + base));
  }

  float inv = s > 0.f ? 1.f / s : 0.f;
  ushort* hp = hbufb + (size_t)node * 256 + off;
  uint uv = (uint)f2bf(aV0 * inv) | ((uint)f2bf(aV1 * inv) << 16);
  uint ub = (uint)f2bf(aB0 * inv) | ((uint)f2bf(aB1 * inv) << 16);
  *(uint*)(hp)       = uv;
  *(uint*)(hp + 128) = ub;
}

// ---------------------------------------------------------------------------
// Kernel 3: out = LN(x + relu(h @ Wo + bo)) * gamma + beta via bf16 MFMA.
// Lean: only Wo chunk in LDS; A-fragments straight from hbufb (verbatim r9).
// ---------------------------------------------------------------------------
__global__ __launch_bounds__(256, 4) void output_mfma(
    const ushort* __restrict__ hbufb, const float* __restrict__ x,
    const float* __restrict__ Wo, const float* __restrict__ bo,
    const float* __restrict__ gamma, const float* __restrict__ beta,
    float* __restrict__ out) {
  __shared__ ushort WB[128 * 136];
  __shared__ float bos[128], gs[128], bts[128];
  int t = threadIdx.x;
  int n0 = blockIdx.x * 128;
  if (t < 128) { bos[t] = bo[t]; gs[t] = gamma[t]; bts[t] = beta[t]; }
  int w = t >> 6, lane = t & 63;
  int m = lane & 15, q = lane >> 4;
  int r0 = w * 32;
  int row0 = n0 + r0 + m;
  int row1 = row0 + 16;
  bool ok0 = row0 < NN, ok1 = row1 < NN;
  const ushort* hr0 = hbufb + (size_t)row0 * 256;
  const ushort* hr1 = hbufb + (size_t)row1 * 256;
  const short8 z8 = (short8){0, 0, 0, 0, 0, 0, 0, 0};

  f32x4 acc0[8], acc1[8];
#pragma unroll
  for (int c = 0; c < 8; ++c) {
    acc0[c] = (f32x4){0.f, 0.f, 0.f, 0.f};
    acc1[c] = (f32x4){0.f, 0.f, 0.f, 0.f};
  }
  for (int kc = 0; kc < 2; ++kc) {
    if (kc) __syncthreads();
    { // stage Wo chunk: rows kc*128..+127 (K), cols 0..127 -> WB[col][k]
      int k = t >> 1, nh = (t & 1) * 64;
      const float* src = Wo + (size_t)(kc * 128 + k) * 128 + nh;
#pragma unroll
      for (int i = 0; i < 16; ++i) {
        float4 f = *(const float4*)(src + 4 * i);
        WB[(nh + 4 * i + 0) * 136 + k] = f2bf(f.x);
        WB[(nh + 4 * i + 1) * 136 + k] = f2bf(f.y);
        WB[(nh + 4 * i + 2) * 136 + k] = f2bf(f.z);
        WB[(nh + 4 * i + 3) * 136 + k] = f2bf(f.w);
      }
    }
    __syncthreads();
#pragma unroll
    for (int kt = 0; kt < 4; ++kt) {
      int kof = kt * 32 + 8 * q;
      short8 a0 = ok0 ? *(const short8*)(hr0 + kc * 128 + kof) : z8;
      short8 a1 = ok1 ? *(const short8*)(hr1 + kc * 128 + kof) : z8;
#pragma unroll
      for (int c = 0; c < 8; ++c) {
        short8 b = *(const short8*)&WB[(c * 16 + m) * 136 + kof];
        acc0[c] = __builtin_amdgcn_mfma_f32_16x16x32_bf16(a0, b, acc0[c], 0, 0, 0);
        acc1[c] = __builtin_amdgcn_mfma_f32_16x16x32_bf16(a1, b, acc1[c], 0, 0, 0);
      }
    }
  }
  // epilogue: relu + residual + LayerNorm, all in registers
#pragma unroll
  for (int half = 0; half < 2; ++half) {
#pragma unroll
    for (int reg = 0; reg < 4; ++reg) {
      int row = n0 + r0 + half * 16 + 4 * q + reg;
      bool valid = row < NN;
      float vals[8];
      float sum = 0.f;
#pragma unroll
      for (int c = 0; c < 8; ++c) {
        int col = c * 16 + m;
        float a = (half ? acc1[c][reg] : acc0[c][reg]) + bos[col];
        a = fmaxf(a, 0.f);
        float xv = valid ? x[(size_t)row * 128 + col] : 0.f;
        float v = a + xv;
        vals[c] = v;
        sum += v;
      }
      sum += __shfl_xor(sum, 1); sum += __shfl_xor(sum, 2);
      sum += __shfl_xor(sum, 4); sum += __shfl_xor(sum, 8);
      float mean = sum * (1.f / 128.f);
      float ssq = 0.f;
#pragma unroll
      for (int c = 0; c < 8; ++c) {
        float d = vals[c] - mean;
        ssq = fmaf(d, d, ssq);
      }
      ssq += __shfl_xor(ssq, 1); ssq += __shfl_xor(ssq, 2);
      ssq += __shfl_xor(ssq, 4); ssq += __shfl_xor(ssq, 8);
      float rstd = rsqrtf(ssq * (1.f / 128.f) + 1e-5f);
      if (valid) {
#pragma unroll
        for (int c = 0; c < 8; ++c) {
          int col = c * 16 + m;
          out[(size_t)row * 128 + col] = (vals[c] - mean) * rstd * gs[col] + bts[col];
        }
      }
    }
  }
}

// ---------------------------------------------------------------------------
extern "C" void kernel_launch(void* const* d_in, const int* in_sizes, int n_in,
                              void* d_out, int out_size, void* d_ws, size_t ws_size,
                              hipStream_t stream) {
  const float* x     = (const float*)d_in[0];
  const int*   ei    = (const int*)d_in[1];
  const float* Wq    = (const float*)d_in[2];
  const float* bq    = (const float*)d_in[3];
  const float* Wk    = (const float*)d_in[4];
  const float* bk    = (const float*)d_in[5];
  const float* Wv    = (const float*)d_in[6];
  const float* bv    = (const float*)d_in[7];
  const float* Wpsi  = (const float*)d_in[8];
  const float* bpsi  = (const float*)d_in[9];
  const float* Wo    = (const float*)d_in[10];
  const float* bo    = (const float*)d_in[11];
  const float* gamma = (const float*)d_in[12];
  const float* beta  = (const float*)d_in[13];
  float* out = (float*)d_out;

  char* ws = (char*)d_ws;
  float*  qbuf   = (float*) (ws);               // 10,240,000 B
  ushort* kbuf   = (ushort*)(ws + 10240000);    //  5,120,000 B
  ushort* vbuf   = (ushort*)(ws + 15360000);    //  5,120,000 B
  ushort* bbuf   = (ushort*)(ws + 20480000);    //  5,120,000 B
  ushort* hbufb  = (ushort*)(ws + 25600000);    // 10,240,000 B
  int*    cursor = (int*)   (ws + 35840000);    //     80,000 B
  ushort* scol   = (ushort*)(ws + 35920000);    //  5,120,000 B  (~41.0 MB)

  hipMemsetAsync(cursor, 0, 80000, stream);

  qkv_gemm<<<dim3(157, 3), 256, 0, stream>>>(x, Wq, bq, Wk, bk, Wv, bv,
                                             Wpsi, bpsi, ei, qbuf,
                                             kbuf, vbuf, bbuf, cursor, scol);
  aggregate_kernel<<<5000, 256, 0, stream>>>(qbuf, kbuf, vbuf, bbuf,
                                             cursor, scol, hbufb);
  output_mfma<<<157, 256, 0, stream>>>(hbufb, x, Wo, bo, gamma, beta, out);
}